// Round 7
// baseline (656.137 us; speedup 1.0000x reference)
//
#include <hip/hip_runtime.h>
#include <hip/hip_fp16.h>
#include <stdint.h>

// Problem constants (LLaMA-7B up-proj, tokens=4096)
#define TOKENS 4096
#define OFEAT  11008
#define IFEAT  4096
#define NGRP   64
#define NGTOT  (OFEAT*NGRP)  // 704512 groups

// GEMM tiling: 256x256 tile, BK=32, 8 waves (2Mx4N), triple-buffered LDS
#define BM 256
#define BN 256
#define BK 32
#define NT_M (TOKENS/BM)   // 16
#define NT_N (OFEAT/BN)    // 43
#define NWG  (NT_M*NT_N)   // 688 (divisible by 8 -> XCD swizzle bijective)
#define NKT  (IFEAT/BK)    // 128 K-tiles

typedef _Float16 half8 __attribute__((ext_vector_type(8)));
typedef float    floatx4 __attribute__((ext_vector_type(4)));

#define AS1 __attribute__((address_space(1)))
#define AS3 __attribute__((address_space(3)))

__device__ __forceinline__ void gload16(const void* g, void* l) {
  // async global->LDS: LDS dest = wave-uniform base + lane*16 (linear),
  // global source per-lane (m104/m108). Source carries the inverse swizzle.
  __builtin_amdgcn_global_load_lds((const AS1 uint32_t*)g, (AS3 uint32_t*)l, 16, 0, 0);
}

// ---------------- pass 1: x fp32 -> f16 ----------------
__global__ __launch_bounds__(256) void cvt_x(const float* __restrict__ x,
                                             _Float16* __restrict__ xh) {
  int t = blockIdx.x * 256 + threadIdx.x;
  const float4* x4 = (const float4*)x;
  float4 a = x4[2*t], c = x4[2*t + 1];
  half8 h;
  h[0] = (_Float16)a.x; h[1] = (_Float16)a.y; h[2] = (_Float16)a.z; h[3] = (_Float16)a.w;
  h[4] = (_Float16)c.x; h[5] = (_Float16)c.y; h[6] = (_Float16)c.z; h[7] = (_Float16)c.w;
  *(half8*)(xh + (size_t)t * 8) = h;
}

// ---------------- pass 2: dequant packed 4-bit -> f16 W[O][I] ----------------
// byte b of group = (q[b] << 4) | q[b+32];  w = q*inv_scale + mn
__global__ __launch_bounds__(256) void dequant_w(const void* __restrict__ packed,
                                                 const float* __restrict__ mn,
                                                 const float* __restrict__ inv_scale,
                                                 _Float16* __restrict__ W) {
  int t = blockIdx.x * 256 + threadIdx.x;
  int g = t >> 3;
  int s = t & 7;

  // int32-widened vs raw-uint8 detection (false-positive prob ~(1e-6)^8)
  __shared__ int is_i32_s;
  if (threadIdx.x == 0) {
    const int* pi = (const int*)packed;
    int ok = 1;
#pragma unroll
    for (int i = 0; i < 8; ++i) ok &= ((unsigned)pi[i] < 256u);
    is_i32_s = ok;
  }
  __syncthreads();

  const int hi = (s < 4) ? 1 : 0;
  const int bbase = (s & 3) * 8;
  unsigned char b[8];
  if (is_i32_s) {
    const int4* p = (const int4*)packed + ((size_t)g * 32 + bbase) / 4;
    int4 w0 = p[0], w1 = p[1];
    b[0] = (unsigned char)w0.x; b[1] = (unsigned char)w0.y;
    b[2] = (unsigned char)w0.z; b[3] = (unsigned char)w0.w;
    b[4] = (unsigned char)w1.x; b[5] = (unsigned char)w1.y;
    b[6] = (unsigned char)w1.z; b[7] = (unsigned char)w1.w;
  } else {
    const unsigned char* p8 = (const unsigned char*)packed + (size_t)g * 32 + bbase;
    uint2 w = *(const uint2*)p8;
    b[0] = w.x & 0xff; b[1] = (w.x >> 8) & 0xff; b[2] = (w.x >> 16) & 0xff; b[3] = (w.x >> 24) & 0xff;
    b[4] = w.y & 0xff; b[5] = (w.y >> 8) & 0xff; b[6] = (w.y >> 16) & 0xff; b[7] = (w.y >> 24) & 0xff;
  }

  float m  = mn[g];
  float sc = inv_scale[g];
  int shift = hi ? 4 : 0;
  half8 h;
#pragma unroll
  for (int j = 0; j < 8; ++j) {
    unsigned q = (b[j] >> shift) & 0xF;
    h[j] = (_Float16)fmaf((float)q, sc, m);
  }
  size_t off = (size_t)g * 64 + (hi ? 0 : 32) + (s & 3) * 8;
  *(half8*)(W + off) = h;
}

// ---------------- pass 3: GEMM C = A @ B^T + bias ----------------
// 256x256 tile, BK=32, 8 waves (2Mx4N, wave tile 128x64), triple-buffered
// 96KB LDS, counted vmcnt(4) (prefetch distance 2 K-tiles), T2 XOR swizzle,
// m201-style two-stroke phases: [reads+stage] barrier lgkmcnt(0) schedbar
// [16 MFMA] barrier -- twice per K-tile, WAITBAR4 doubles as stroke-B close.

#define MFMA16(a, b, c) __builtin_amdgcn_mfma_f32_16x16x32_f16((a), (b), (c), 0, 0, 0)

// fused wait+barrier: single asm so nothing slips between drain and barrier
#define WAITBAR4() asm volatile("s_waitcnt vmcnt(4)\n\ts_barrier" ::: "memory")
#define WAITBAR0() asm volatile("s_waitcnt vmcnt(0)\n\ts_barrier" ::: "memory")
// opening fence: all this wave's ds_reads resident, and keep MFMAs below it
// (rule #18: inline-asm lgkmcnt needs a following sched_barrier(0), else
// hipcc hoists register-only MFMAs above the wait)
#define LGKM0_FENCE() do { \
    asm volatile("s_waitcnt lgkmcnt(0)" ::: "memory"); \
    __builtin_amdgcn_sched_barrier(0); \
  } while (0)

// One K-tile: two strokes.
// Stroke A: 8 ds_read (af0-3, bf0-3) + stage A(t+2) | barrier | lgkm0 |
//           16 MFMA (fr0-3 x fc0-3) | barrier.
// Stroke B: 4 ds_read (af4-7) + stage B(t+2) | barrier | lgkm0 |
//           16 MFMA (fr4-7, bf reused) | WAITBAR4 (close + confirm t+1).
__device__ __forceinline__ void tile_body(const _Float16* bA, const _Float16* bB,
                                          const char* ga, const char* gb,
                                          char* lA2, char* lB2,
                                          floatx4 (&acc)[8][4],
                                          int lofs, int arow, int brow, size_t K2) {
  half8 af[4], bf[4];
  // ---- stroke A: read + stage ----
#pragma unroll
  for (int fr = 0; fr < 4; ++fr)
    af[fr] = *(const half8*)(bA + (arow + fr * 16) * 32 + lofs);
#pragma unroll
  for (int fc = 0; fc < 4; ++fc)
    bf[fc] = *(const half8*)(bB + (brow + fc * 16) * 32 + lofs);
  gload16(ga,            lA2);
  gload16(ga + 128 * K2, lA2 + 8192);
  __builtin_amdgcn_s_barrier();
  LGKM0_FENCE();
  __builtin_amdgcn_s_setprio(1);
#pragma unroll
  for (int fr = 0; fr < 4; ++fr)
#pragma unroll
    for (int fc = 0; fc < 4; ++fc)
      acc[fr][fc] = MFMA16(af[fr], bf[fc], acc[fr][fc]);
  __builtin_amdgcn_s_setprio(0);
  __builtin_amdgcn_s_barrier();          // close stroke A
  // ---- stroke B: read + stage ----
  half8 ag[4];
#pragma unroll
  for (int fr = 0; fr < 4; ++fr)
    ag[fr] = *(const half8*)(bA + (arow + 64 + fr * 16) * 32 + lofs);
  gload16(gb,            lB2);
  gload16(gb + 128 * K2, lB2 + 8192);
  __builtin_amdgcn_s_barrier();
  LGKM0_FENCE();
  __builtin_amdgcn_s_setprio(1);
#pragma unroll
  for (int fr = 0; fr < 4; ++fr)
#pragma unroll
    for (int fc = 0; fc < 4; ++fc)
      acc[4 + fr][fc] = MFMA16(ag[fr], bf[fc], acc[4 + fr][fc]);
  __builtin_amdgcn_s_setprio(0);
  WAITBAR4();                            // close stroke B + confirm tile t+1
}

// epilogue compute (no staging)
__device__ __forceinline__ void compute_full(const _Float16* bA, const _Float16* bB,
                                             floatx4 (&acc)[8][4],
                                             int lofs, int arow, int brow) {
  half8 af[8], bf[4];
#pragma unroll
  for (int fr = 0; fr < 8; ++fr)
    af[fr] = *(const half8*)(bA + (arow + fr * 16) * 32 + lofs);
#pragma unroll
  for (int fc = 0; fc < 4; ++fc)
    bf[fc] = *(const half8*)(bB + (brow + fc * 16) * 32 + lofs);
  LGKM0_FENCE();
  __builtin_amdgcn_s_setprio(1);
#pragma unroll
  for (int fr = 0; fr < 8; ++fr)
#pragma unroll
    for (int fc = 0; fc < 4; ++fc)
      acc[fr][fc] = MFMA16(af[fr], bf[fc], acc[fr][fc]);
  __builtin_amdgcn_s_setprio(0);
}

__global__ __launch_bounds__(512, 2) void gemm_f16(const _Float16* __restrict__ A,
                                                   const _Float16* __restrict__ B,
                                                   const float* __restrict__ bias,
                                                   float* __restrict__ C) {
  __shared__ __align__(16) _Float16 smem[3 * 16384];   // 96 KiB

  int bid = blockIdx.x;
  int swz = (bid & 7) * (NWG >> 3) + (bid >> 3);   // XCD-aware, bijective
  int tm = swz / NT_N, tn = swz % NT_N;

  int tid  = threadIdx.x;
  int wave = tid >> 6, lane = tid & 63;
  int wm = wave >> 2, wn = wave & 3;       // 2M x 4N waves, wave tile 128x64

  // staging: thread t covers LDS bytes t*16 of each 8KB half (linear dest);
  // source pre-swizzled: k-slot = (t&3) ^ ((t>>3)&3)  (m97/m104 + rule 21)
  const size_t K2 = (size_t)IFEAT * 2;
  int kswz = (((tid & 3) ^ ((tid >> 3) & 3)) << 4);
  const char* gA = (const char*)A + (size_t)(tm * BM + (tid >> 2)) * K2 + kswz;
  const char* gB = (const char*)B + (size_t)(tn * BN + (tid >> 2)) * K2 + kswz;

  int dstoff = wave * 1024;                // wave-uniform LDS dest offset
  _Float16* A0 = smem;              _Float16* B0 = smem + 8192;
  _Float16* A1 = smem + 16384;      _Float16* B1 = smem + 24576;
  _Float16* A2 = smem + 32768;      _Float16* B2 = smem + 40960;
  char* lA0 = (char*)A0 + dstoff;  char* lB0 = (char*)B0 + dstoff;
  char* lA1 = (char*)A1 + dstoff;  char* lB1 = (char*)B1 + dstoff;
  char* lA2 = (char*)A2 + dstoff;  char* lB2 = (char*)B2 + dstoff;

  // fragment read: lane l -> row R+(l&15), physical slot (l>>4)^(((l&15)>>1)&3)
  int x = lane & 15;
  int pslot = (lane >> 4) ^ ((x >> 1) & 3);
  int lofs = x * 32 + pslot * 8;           // f16 units (row stride 32)
  const int arow = wm * 128;
  const int brow = wn * 64;

  floatx4 acc[8][4] = {};

  // prologue: stage tiles 0,1; drain to 4 (tile 0 confirmed)
  gload16(gA,            lA0);  gload16(gA + 128 * K2, lA0 + 8192);
  gload16(gB,            lB0);  gload16(gB + 128 * K2, lB0 + 8192);
  gload16(gA + 64,       lA1);  gload16(gA + 64 + 128 * K2, lA1 + 8192);
  gload16(gB + 64,       lB1);  gload16(gB + 64 + 128 * K2, lB1 + 8192);
  WAITBAR4();

  // main loop: 42 iterations x 3 tiles. Invariant at body entry: tile t
  // confirmed, t+1's 4 loads outstanding. Body stages t+2, computes t,
  // drains to 4 (confirms t+1). Buffer (t+2)%3 sealed since end of t-1.
  for (int t = 0; t < NKT - 2; t += 3) {
    const char* a = gA + (size_t)(t + 2) * 64;
    const char* b = gB + (size_t)(t + 2) * 64;
    tile_body(A0, B0, a,       b,       lA2, lB2, acc, lofs, arow, brow, K2);
    tile_body(A1, B1, a + 64,  b + 64,  lA0, lB0, acc, lofs, arow, brow, K2);
    tile_body(A2, B2, a + 128, b + 128, lA1, lB1, acc, lofs, arow, brow, K2);
  }
  // tiles 126 (buf0, confirmed) and 127 (buf1, in flight)
  compute_full(A0, B0, acc, lofs, arow, brow);
  WAITBAR0();
  compute_full(A1, B1, acc, lofs, arow, brow);

  // epilogue: C/D layout col = lane&15, row = (lane>>4)*4 + reg
  int rowq = (lane >> 4) << 2;
  int colbase = tn * BN + brow + x;
#pragma unroll
  for (int fc = 0; fc < 4; ++fc) {
    int col = colbase + fc * 16;
    float bv = bias[col];
#pragma unroll
    for (int fr = 0; fr < 8; ++fr) {
      int row = tm * BM + arow + fr * 16 + rowq;
#pragma unroll
      for (int p = 0; p < 4; ++p)
        C[(size_t)(row + p) * OFEAT + col] = acc[fr][fc][p] + bv;
    }
  }
}

extern "C" void kernel_launch(void* const* d_in, const int* in_sizes, int n_in,
                              void* d_out, int out_size, void* d_ws, size_t ws_size,
                              hipStream_t stream) {
  const float* x         = (const float*)d_in[0];
  const void*  packed    = d_in[1];
  const float* mn        = (const float*)d_in[2];
  const float* inv_scale = (const float*)d_in[3];
  const float* bias      = (const float*)d_in[4];
  float* out = (float*)d_out;

  _Float16* xh = (_Float16*)d_ws;
  _Float16* wh = (_Float16*)((char*)d_ws + (size_t)TOKENS * IFEAT * 2);

  cvt_x<<<(TOKENS * IFEAT) / (256 * 8), 256, 0, stream>>>(x, xh);
  dequant_w<<<(NGTOT * 8) / 256, 256, 0, stream>>>(packed, mn, inv_scale, wh);
  gemm_f16<<<NWG, 512, 0, stream>>>(xh, wh, bias, out);
}